// Round 2
// baseline (1440.245 us; speedup 1.0000x reference)
//
#include <hip/hip_runtime.h>
#include <math.h>

// LogEntmaxBisect: out = log(entmax_bisect(X, alpha=1.5)) row-wise over last dim.
// v3: v1 structure (one row per block, row in registers, grid=4096) with the
// exposed compute minimized:
//  - stats pass for tau0 (tau=-inf, k=D const) fused into the load loop, so it
//    hides under HBM load latency; dense data => the single in-loop refinement
//    pass reproduces identical stats and breaks immediately (v1 ran 3 passes).
//  - S computed in closed form from the converged stats
//    (S = q - 2*tau*s1 + k*tau^2), deleting the S pass + 2 barriers.
//  - __launch_bounds__(640,5) caps VGPR at 102 -> 5 waves/SIMD -> 2 blocks/CU
//    resident, so the remaining ~0.8us/row of barrier-synced compute is hidden
//    by the co-resident block's memory phases.
// Kernel is read-once + write-once: floor ~166 us at 6.3 TB/s.
// (v2's in-loop prefetch regressed: per-iteration vmcnt waits serialized the
// loads and the extra live registers crossed the 2-blocks/CU VGPR cliff.)

constexpr int D     = 32000;          // row length
constexpr int BLOCK = 640;            // 10 waves
constexpr int NW    = BLOCK / 64;     // 10
constexpr int VPT   = D / BLOCK;      // 50 floats per thread
constexpr int V2    = VPT / 2;        // 25 float2 per thread

__global__ __launch_bounds__(BLOCK, 5) void
log_entmax_kernel(const float* __restrict__ X, float* __restrict__ out) {
    const int row  = blockIdx.x;
    const int tid  = threadIdx.x;
    const int lane = tid & 63;
    const int wave = tid >> 6;

    __shared__ float red[NW][4];      // [wave][{k, s1, q, -}]

    const float2* __restrict__ src = reinterpret_cast<const float2*>(X + (size_t)row * D);
    float2* __restrict__       dst = reinterpret_cast<float2*>(out + (size_t)row * D);

    // Load row into registers (Xs = 0.5 * X, alpha-1 = 0.5) and fuse the
    // full-support stats pass (tau=-inf => no compare; k = D is a constant).
    float xs[VPT];
    float s1 = 0.f, q = 0.f;
#pragma unroll
    for (int j = 0; j < V2; ++j) {
        float2 v = src[j * BLOCK + tid];
        float a = 0.5f * v.x;
        float b = 0.5f * v.y;
        xs[2 * j]     = a;
        xs[2 * j + 1] = b;
        s1 += a + b;
        q  += a * a + b * b;
    }
#pragma unroll
    for (int o = 32; o > 0; o >>= 1) {
        s1 += __shfl_down(s1, o);
        q  += __shfl_down(q, o);
    }
    if (lane == 0) { red[wave][1] = s1; red[wave][2] = q; }
    __syncthreads();
    s1 = 0.f; q = 0.f;
#pragma unroll
    for (int w = 0; w < NW; ++w) { s1 += red[w][1]; q += red[w][2]; }
    __syncthreads();                  // red reused by refinement loop

    float k = (float)D;
    float tau;
    {
        float mu   = s1 / k;
        float disc = mu * mu - (q - 1.0f) / k;
        tau = mu - sqrtf(fmaxf(disc, 0.0f));
    }

    // Support refinement: support = {i : Xs_i > tau};
    //   tau = mu - sqrt(mu^2 - (Q-1)/k).  Block-uniform, no divergence.
    // Dense support (tau0 < min Xs) -> first pass reproduces the full-support
    // stats -> tnew == tau -> break with stats matching the final tau.
    for (int it = 0; it < 16; ++it) {
        float kk = 0.f, ss = 0.f, qq = 0.f;
#pragma unroll
        for (int j = 0; j < VPT; ++j) {
            float v = xs[j];
            if (v > tau) { kk += 1.f; ss += v; qq += v * v; }
        }
#pragma unroll
        for (int o = 32; o > 0; o >>= 1) {
            kk += __shfl_down(kk, o);
            ss += __shfl_down(ss, o);
            qq += __shfl_down(qq, o);
        }
        if (lane == 0) { red[wave][0] = kk; red[wave][1] = ss; red[wave][2] = qq; }
        __syncthreads();
        kk = 0.f; ss = 0.f; qq = 0.f;
#pragma unroll
        for (int w = 0; w < NW; ++w) {
            kk += red[w][0]; ss += red[w][1]; qq += red[w][2];
        }

        float mu   = ss / kk;
        float disc = mu * mu - (qq - 1.0f) / kk;
        float tnew = mu - sqrtf(fmaxf(disc, 0.0f));

        k = kk; s1 = ss; q = qq;      // stats corresponding to current tau
        if (tnew == tau) break;       // uniform: identical on all threads
        tau = tnew;
        __syncthreads();              // red rewritten next iteration
    }

    // Normalization in closed form from the converged stats:
    // S = sum_supp (Xs - tau)^2 = q - 2*tau*s1 + k*tau^2  (~= 1 by construction)
    const float S  = q - 2.f * tau * s1 + k * tau * tau;
    const float lS = __logf(S);

    // out = log(p) = 2*log(relu(Xs - tau)) - log(S)
#pragma unroll
    for (int j = 0; j < V2; ++j) {
        float z0 = fmaxf(xs[2 * j]     - tau, 0.f);
        float z1 = fmaxf(xs[2 * j + 1] - tau, 0.f);
        float2 o;
        o.x = 2.f * __logf(z0) - lS;
        o.y = 2.f * __logf(z1) - lS;
        dst[j * BLOCK + tid] = o;
    }
}

extern "C" void kernel_launch(void* const* d_in, const int* in_sizes, int n_in,
                              void* d_out, int out_size, void* d_ws, size_t ws_size,
                              hipStream_t stream) {
    const float* X = (const float*)d_in[0];
    float* out     = (float*)d_out;
    const int rows = in_sizes[0] / D;   // 4096
    log_entmax_kernel<<<rows, BLOCK, 0, stream>>>(X, out);
}